// Round 12
// baseline (231.588 us; speedup 1.0000x reference)
//
#include <hip/hip_runtime.h>
#include <hip/hip_fp16.h>

#define GAT_H 4
#define GAT_HC 64
#define NEG_SLOPE 0.2f
#define DB 128            // dsts per bin
#define NBMAX 512         // max bins (requires N <= 65536; here N=50000 -> 391)
#define CHUNK 4096        // edges per bin_scatter block
#define EPT 16            // edges per thread in bin_scatter

__device__ __forceinline__ float lrelu(float x) { return x >= 0.f ? x : NEG_SLOPE * x; }

// ---- h = x@W [N,64] (fp16 out); fused per-node attention logits a_src,a_dst [N,4] ----
// Wave-per-row: W column in K VGPRs; x row wave-uniform -> scalar pipe loads.
template <int K, bool CONCAT>
__global__ __launch_bounds__(256) void gemm_attn(
    const float* __restrict__ x, const float* __restrict__ nf,
    const float* __restrict__ gf, const int* __restrict__ batch,
    const float* __restrict__ W,
    const float* __restrict__ att_s, const float* __restrict__ att_d,
    __half* __restrict__ h, float* __restrict__ asrc, float* __restrict__ adst,
    int N, int nwaves)
{
    int lane = threadIdx.x & 63;
    int wid = blockIdx.x * 4 + __builtin_amdgcn_readfirstlane(threadIdx.x >> 6);

    float w[K];
    #pragma unroll
    for (int k = 0; k < K; ++k) w[k] = W[k * 64 + lane];
    float as_c = att_s[lane];
    float ad_c = att_d[lane];

    for (int row = wid; row < N; row += nwaves) {
        float acc = 0.f;
        if (CONCAT) {
            #pragma unroll
            for (int k = 0; k < 9; ++k) acc = fmaf(nf[row * 9 + k], w[k], acc);
            int b = batch[row];
            #pragma unroll
            for (int k = 0; k < 4; ++k) acc = fmaf(gf[b * 4 + k], w[9 + k], acc);
        } else {
            #pragma unroll
            for (int k = 0; k < K; ++k) acc = fmaf(x[(size_t)row * K + k], w[k], acc);
        }
        h[(unsigned)row * 64u + (unsigned)lane] = __float2half(acc);
        float vs = acc * as_c;
        float vd = acc * ad_c;
        #pragma unroll
        for (int off = 8; off; off >>= 1) { vs += __shfl_xor(vs, off); vd += __shfl_xor(vd, off); }
        if ((lane & 15) == 0) {
            asrc[row * GAT_H + (lane >> 4)] = vs;
            adst[row * GAT_H + (lane >> 4)] = vd;
        }
    }
}

// ==================== binned CSR build ====================

// zero bin_cnt + bin_fill without hipMemsetAsync (a small fill costs ~43us in-graph)
__global__ __launch_bounds__(256) void zero_small(unsigned* __restrict__ bin_cnt,
                                                  unsigned* __restrict__ bin_fill)
{
    int t = threadIdx.x;
    bin_cnt[t] = 0; bin_cnt[t + 256] = 0;
    bin_fill[t] = 0; bin_fill[t + 256] = 0;
}

__global__ __launch_bounds__(256) void hist_bins(const int* __restrict__ dst,
                                                 unsigned* __restrict__ bin_cnt, int E)
{
    __shared__ unsigned lh[NBMAX];
    int t = threadIdx.x;
    lh[t] = 0; lh[t + 256] = 0;
    __syncthreads();
    for (int e = blockIdx.x * 256 + t; e < E; e += gridDim.x * 256)
        atomicAdd(&lh[((unsigned)dst[e]) >> 7], 1u);
    __syncthreads();
    unsigned v = lh[t];       if (v) atomicAdd(&bin_cnt[t], v);
    v = lh[t + 256];          if (v) atomicAdd(&bin_cnt[t + 256], v);
}

__global__ __launch_bounds__(256) void scan_bins(const unsigned* __restrict__ bin_cnt,
                                                 unsigned* __restrict__ bin_base,
                                                 int* __restrict__ indptr,
                                                 int nb, int N, int E)
{
    __shared__ unsigned buf[NBMAX];
    int t = threadIdx.x;
    buf[t] = (t < nb) ? bin_cnt[t] : 0u;
    buf[t + 256] = (t + 256 < nb) ? bin_cnt[t + 256] : 0u;
    __syncthreads();
    for (int off = 1; off < NBMAX; off <<= 1) {
        unsigned a = 0, b = 0;
        if (t >= off) a = buf[t - off];
        b = buf[t + 256 - off];
        __syncthreads();
        buf[t] += a; buf[t + 256] += b;
        __syncthreads();
    }
    if (t == 0) { bin_base[0] = 0; indptr[N] = E; }
    if (t < nb) bin_base[t + 1] = buf[t];
    if (t + 256 < nb) bin_base[t + 257] = buf[t + 256];
}

// chunk-local LDS sort by bin, then run-coalesced scatter into bin segments.
// packed edge = (dst<<16)|src  (requires N <= 65536); bin = packed>>23.
__global__ __launch_bounds__(256) void bin_scatter(const int* __restrict__ src,
                                                   const int* __restrict__ dst,
                                                   const unsigned* __restrict__ bin_base,
                                                   unsigned* __restrict__ bin_fill,
                                                   unsigned* __restrict__ binned, int E)
{
    __shared__ unsigned lh[NBMAX];
    __shared__ int goff[NBMAX];
    __shared__ unsigned sorted[CHUNK];
    int t = threadIdx.x;
    lh[t] = 0; lh[t + 256] = 0;
    __syncthreads();
    int e0 = blockIdx.x * CHUNK;

    unsigned pk[EPT]; int bn[EPT]; unsigned rk[EPT];
    #pragma unroll
    for (int i = 0; i < EPT; ++i) {
        int e = e0 + i * 256 + t;
        bn[i] = -1;
        if (e < E) {
            unsigned d = (unsigned)dst[e];
            pk[i] = (d << 16) | (unsigned)src[e];
            bn[i] = (int)(d >> 7);
            rk[i] = atomicAdd(&lh[bn[i]], 1u);
        }
    }
    __syncthreads();
    unsigned c0 = lh[t], c1 = lh[t + 256];   // own-bin counts (pre-scan)
    for (int off = 1; off < NBMAX; off <<= 1) {
        unsigned a = 0, b = 0;
        if (t >= off) a = lh[t - off];
        b = lh[t + 256 - off];
        __syncthreads();
        lh[t] += a; lh[t + 256] += b;
        __syncthreads();
    }
    unsigned x0 = lh[t] - c0, x1 = lh[t + 256] - c1;   // exclusive local bases
    if (c0) { unsigned g = atomicAdd(&bin_fill[t], c0);
              goff[t] = (int)(bin_base[t] + g) - (int)x0; }
    if (c1) { unsigned g = atomicAdd(&bin_fill[t + 256], c1);
              goff[t + 256] = (int)(bin_base[t + 256] + g) - (int)x1; }
    lh[t] = x0; lh[t + 256] = x1;            // own-entry overwrite only
    __syncthreads();
    #pragma unroll
    for (int i = 0; i < EPT; ++i)
        if (bn[i] >= 0) sorted[lh[bn[i]] + rk[i]] = pk[i];
    __syncthreads();
    int T = min(CHUNK, E - e0);
    for (int j = t; j < T; j += 256) {
        unsigned p = sorted[j];
        binned[goff[p >> 23] + j] = p;       // piecewise-contiguous runs
    }
}

// block per bin; LDS counting-sort by dst_local -> final dst-sorted csr_src + indptr
__global__ __launch_bounds__(256) void bin_finalize(const unsigned* __restrict__ binned,
                                                    const unsigned* __restrict__ bin_base,
                                                    int* __restrict__ csr_src,
                                                    int* __restrict__ indptr, int N)
{
    __shared__ unsigned lh[DB];
    __shared__ unsigned fill[DB];
    int t = threadIdx.x, b = blockIdx.x;
    unsigned base = bin_base[b];
    unsigned cnt = bin_base[b + 1] - base;
    if (t < DB) lh[t] = 0;
    __syncthreads();
    for (unsigned i = t; i < cnt; i += 256)
        atomicAdd(&lh[(binned[base + i] >> 16) & (DB - 1)], 1u);
    __syncthreads();
    unsigned c0 = (t < DB) ? lh[t] : 0;
    for (int off = 1; off < DB; off <<= 1) {
        unsigned a = 0;
        if (t >= off && t < DB) a = lh[t - off];
        __syncthreads();
        if (t < DB) lh[t] += a;
        __syncthreads();
    }
    if (t < DB) {
        unsigned excl = lh[t] - c0;
        int d = b * DB + t;
        if (d < N) indptr[d] = (int)(base + excl);
        fill[t] = excl;
    }
    __syncthreads();
    for (unsigned i = t; i < cnt; i += 256) {
        unsigned p = binned[base + i];
        unsigned pos = atomicAdd(&fill[(p >> 16) & (DB - 1)], 1u);
        csr_src[base + pos] = (int)(p & 0xFFFFu);
    }
}

// ==================== aggregation: 16-edge x 4-head lane mapping ====================
// Wave per node. lane = eslot*4 + s (eslot=edge slot 0..15, s=head 0..3).
// Each lane loads a 32B fp16 chunk (16 channels of head s) of ITS edge's h row:
// one dwordx4 instruction touches ~16 distinct lines -> ~64 lines in flight/wave.
// Virtual edge 0 = self loop; tail lanes exec-masked. Per-lane acc[16] folded by
// one shfl_xor tree per node.
template <bool RELU>
__global__ __launch_bounds__(256) void aggregate(
    const __half* __restrict__ h, const float* __restrict__ asrc,
    const float* __restrict__ adst, const int* __restrict__ indptr,
    const int* __restrict__ csr_src, const float* __restrict__ bias,
    float* __restrict__ xout, int N, int nwaves)
{
    int lane = threadIdx.x & 63;
    int wid = blockIdx.x * 4 + __builtin_amdgcn_readfirstlane(threadIdx.x >> 6);
    int eslot = lane >> 2;              // 0..15
    unsigned s = (unsigned)(lane & 3);  // head

    float4 bias_r[4];                   // bias[s*16 + 0..15]
    #pragma unroll
    for (int c = 0; c < 4; ++c)
        bias_r[c] = reinterpret_cast<const float4*>(bias)[s * 4u + c];

    for (int node = wid; node < N; node += nwaves) {
        int beg = __builtin_amdgcn_readfirstlane(indptr[node]);
        int end = __builtin_amdgcn_readfirstlane(indptr[node + 1]);
        int total = (end - beg) + 1;    // + self loop (virtual idx 0)

        float adst_n = adst[(unsigned)node * 4u + s];
        float sacc = 0.f;
        float acc[16];
        #pragma unroll
        for (int i = 0; i < 16; ++i) acc[i] = 0.f;

        for (int g0 = 0; g0 < total; g0 += 16) {
            int idx = g0 + eslot;
            if (idx < total) {
                int src = (idx == 0) ? node : csr_src[beg + idx - 1];
                float a = asrc[(unsigned)src * 4u + s];
                const uint4* hp =
                    reinterpret_cast<const uint4*>(h + (unsigned)src * 64u + s * 16u);
                uint4 hv0 = hp[0];
                uint4 hv1 = hp[1];
                float p = __expf(lrelu(a + adst_n));
                sacc += p;
                const __half2* hh0 = reinterpret_cast<const __half2*>(&hv0);
                const __half2* hh1 = reinterpret_cast<const __half2*>(&hv1);
                #pragma unroll
                for (int j = 0; j < 4; ++j) {
                    float2 f0 = __half22float2(hh0[j]);
                    acc[j * 2 + 0] = fmaf(f0.x, p, acc[j * 2 + 0]);
                    acc[j * 2 + 1] = fmaf(f0.y, p, acc[j * 2 + 1]);
                    float2 f1 = __half22float2(hh1[j]);
                    acc[8 + j * 2 + 0] = fmaf(f1.x, p, acc[8 + j * 2 + 0]);
                    acc[8 + j * 2 + 1] = fmaf(f1.y, p, acc[8 + j * 2 + 1]);
                }
            }
        }

        // fold the 16 edge slots (lane bits 2..5)
        #pragma unroll
        for (int off = 4; off <= 32; off <<= 1) {
            sacc += __shfl_xor(sacc, off);
            #pragma unroll
            for (int i = 0; i < 16; ++i) acc[i] += __shfl_xor(acc[i], off);
        }

        if (eslot == 0) {               // lanes 0..3 write head s's 16 channels
            float inv = 1.0f / sacc;
            float4* op = reinterpret_cast<float4*>(xout + (unsigned)node * 64u + s * 16u);
            #pragma unroll
            for (int c = 0; c < 4; ++c) {
                float4 o;
                o.x = fmaf(acc[c * 4 + 0], inv, bias_r[c].x);
                o.y = fmaf(acc[c * 4 + 1], inv, bias_r[c].y);
                o.z = fmaf(acc[c * 4 + 2], inv, bias_r[c].z);
                o.w = fmaf(acc[c * 4 + 3], inv, bias_r[c].w);
                if (RELU) {
                    o.x = fmaxf(o.x, 0.f); o.y = fmaxf(o.y, 0.f);
                    o.z = fmaxf(o.z, 0.f); o.w = fmaxf(o.w, 0.f);
                }
                op[c] = o;
            }
        }
    }
}

// ---- fused scatter-mean pooling (batch_idx sorted -> binary search) + MLP head ----
__global__ void pool_mlp(const float* __restrict__ x, const int* __restrict__ batch, int N,
                         const float* __restrict__ W0, const float* __restrict__ b0,
                         const float* __restrict__ W1, const float* __restrict__ b1,
                         const float* __restrict__ W2, const float* __restrict__ b2,
                         const float* __restrict__ W3, const float* __restrict__ b3,
                         float* __restrict__ out)
{
    __shared__ int bounds[2];
    __shared__ float red[4][64];
    __shared__ float hb[64];
    int b = blockIdx.x, t = threadIdx.x;

    if (t < 2) {
        int target = b + t;
        int lo = 0, hi = N;
        while (lo < hi) {
            int mid = (lo + hi) >> 1;
            if (batch[mid] < target) lo = mid + 1; else hi = mid;
        }
        bounds[t] = lo;
    }
    __syncthreads();
    int beg = bounds[0], end = bounds[1];

    int c = t & 63, w = t >> 6;
    float sum = 0.f;
    for (int n = beg + w; n < end; n += 4) sum += x[(size_t)n * 64 + c];
    red[w][c] = sum;
    __syncthreads();
    if (t < 64) {
        float v = red[0][t] + red[1][t] + red[2][t] + red[3][t];
        float cb = fmaxf((float)(end - beg), 1.0f);
        hb[t] = v / cb;
    }
    __syncthreads();

    float v0 = 0.f;
    if (t < 64) {
        v0 = b0[t];
        for (int k = 0; k < 64; ++k) v0 = fmaf(hb[k], W0[k * 64 + t], v0);
        v0 = fmaxf(v0, 0.f);
    }
    __syncthreads(); if (t < 64) hb[t] = v0; __syncthreads();
    if (t < 64) {
        v0 = b1[t];
        for (int k = 0; k < 64; ++k) v0 = fmaf(hb[k], W1[k * 64 + t], v0);
        v0 = fmaxf(v0, 0.f);
    }
    __syncthreads(); if (t < 64) hb[t] = v0; __syncthreads();
    if (t < 64) {
        v0 = b2[t];
        for (int k = 0; k < 64; ++k) v0 = fmaf(hb[k], W2[k * 64 + t], v0);
        v0 = fmaxf(v0, 0.f);
    }
    __syncthreads(); if (t < 64) hb[t] = v0; __syncthreads();
    if (t < 64) {
        float r = hb[t] * W3[t];
        #pragma unroll
        for (int off = 32; off; off >>= 1) r += __shfl_xor(r, off);
        if (t == 0) out[b] = r + b3[0];
    }
}

extern "C" void kernel_launch(void* const* d_in, const int* in_sizes, int n_in,
                              void* d_out, int out_size, void* d_ws, size_t ws_size,
                              hipStream_t stream)
{
    const float* node_feats = (const float*)d_in[0];
    const float* glob       = (const float*)d_in[1];
    const int*   edge_index = (const int*)d_in[2];
    const int*   batch      = (const int*)d_in[3];
    const float* W[3]  = {(const float*)d_in[4],  (const float*)d_in[8],  (const float*)d_in[12]};
    const float* As[3] = {(const float*)d_in[5],  (const float*)d_in[9],  (const float*)d_in[13]};
    const float* Ad[3] = {(const float*)d_in[6],  (const float*)d_in[10], (const float*)d_in[14]};
    const float* Bi[3] = {(const float*)d_in[7],  (const float*)d_in[11], (const float*)d_in[15]};
    const float* mW0 = (const float*)d_in[16]; const float* mb0 = (const float*)d_in[17];
    const float* mW1 = (const float*)d_in[18]; const float* mb1 = (const float*)d_in[19];
    const float* mW2 = (const float*)d_in[20]; const float* mb2 = (const float*)d_in[21];
    const float* mW3 = (const float*)d_in[22]; const float* mb3 = (const float*)d_in[23];
    float* out = (float*)d_out;

    int N = in_sizes[0] / 9;
    int E = in_sizes[2] / 2;
    int B = in_sizes[1] / 4;
    const int* esrc = edge_index;
    const int* edst = edge_index + E;
    int nb = (N + DB - 1) / DB;

    // workspace layout
    char* ws = (char*)d_ws;
    size_t off = 0;
    auto alloc = [&](size_t bytes) -> void* {
        void* p = ws + off;
        off = (off + bytes + 255) & ~(size_t)255;
        return p;
    };
    __half*   hbuf     = (__half*)alloc((size_t)N * 64 * 2);
    float*    xbuf     = (float*)alloc((size_t)N * 64 * 4);
    float*    asrc     = (float*)alloc((size_t)N * GAT_H * 4);
    float*    adst     = (float*)alloc((size_t)N * GAT_H * 4);
    int*      indptr   = (int*)alloc((size_t)(N + 1) * 4);
    int*      csr_src  = (int*)alloc((size_t)E * 4);
    unsigned* binned   = (unsigned*)alloc((size_t)E * 4);
    unsigned* bin_cnt  = (unsigned*)alloc(NBMAX * 4);
    unsigned* bin_base = (unsigned*)alloc((NBMAX + 1) * 4);
    unsigned* bin_fill = (unsigned*)alloc(NBMAX * 4);
    (void)ws_size;

    // CSR build (binned counting sort; once — shared by all 3 layers)
    zero_small<<<1, 256, 0, stream>>>(bin_cnt, bin_fill);
    hist_bins<<<400, 256, 0, stream>>>(edst, bin_cnt, E);
    scan_bins<<<1, 256, 0, stream>>>(bin_cnt, bin_base, indptr, nb, N, E);
    bin_scatter<<<(E + CHUNK - 1) / CHUNK, 256, 0, stream>>>(esrc, edst, bin_base, bin_fill,
                                                             binned, E);
    bin_finalize<<<nb, 256, 0, stream>>>(binned, bin_base, csr_src, indptr, N);

    const int gemmBlocks = 1024;
    const int aggBlocks = 12500;    // 50000 waves -> 1 node per wave
    // layer 0 (K=13, concat fused)
    gemm_attn<13, true><<<gemmBlocks, 256, 0, stream>>>(nullptr, node_feats, glob, batch,
                                                        W[0], As[0], Ad[0], hbuf, asrc, adst,
                                                        N, gemmBlocks * 4);
    aggregate<true><<<aggBlocks, 256, 0, stream>>>(hbuf, asrc, adst, indptr, csr_src, Bi[0],
                                                   xbuf, N, aggBlocks * 4);
    // layer 1 (K=64)
    gemm_attn<64, false><<<gemmBlocks, 256, 0, stream>>>(xbuf, nullptr, nullptr, nullptr,
                                                         W[1], As[1], Ad[1], hbuf, asrc, adst,
                                                         N, gemmBlocks * 4);
    aggregate<true><<<aggBlocks, 256, 0, stream>>>(hbuf, asrc, adst, indptr, csr_src, Bi[1],
                                                   xbuf, N, aggBlocks * 4);
    // layer 2 (K=64, no act)
    gemm_attn<64, false><<<gemmBlocks, 256, 0, stream>>>(xbuf, nullptr, nullptr, nullptr,
                                                         W[2], As[2], Ad[2], hbuf, asrc, adst,
                                                         N, gemmBlocks * 4);
    aggregate<false><<<aggBlocks, 256, 0, stream>>>(hbuf, asrc, adst, indptr, csr_src, Bi[2],
                                                    xbuf, N, aggBlocks * 4);

    // fused pooling + MLP head
    pool_mlp<<<B, 256, 0, stream>>>(xbuf, batch, N,
                                    mW0, mb0, mW1, mb1, mW2, mb2, mW3, mb3, out);
}

// Round 13
// 207.834 us; speedup vs baseline: 1.1143x; 1.1143x over previous
//
#include <hip/hip_runtime.h>
#include <hip/hip_fp16.h>

#define GAT_H 4
#define GAT_HC 64
#define NEG_SLOPE 0.2f
#define DB 128            // dsts per bin
#define NBMAX 512         // max bins (requires N <= 65536; here N=50000 -> 391)
#define CHUNK 4096        // edges per bin_scatter block
#define EPT 16            // edges per thread in bin_scatter

__device__ __forceinline__ float lrelu(float x) { return x >= 0.f ? x : NEG_SLOPE * x; }

// ---- layer-0 GEMM: h = concat(nf,gf[batch]) @ W (fp16 out); fused logits ----
template <int K>
__global__ __launch_bounds__(256) void gemm0_attn(
    const float* __restrict__ nf, const float* __restrict__ gf,
    const int* __restrict__ batch, const float* __restrict__ W,
    const float* __restrict__ att_s, const float* __restrict__ att_d,
    __half* __restrict__ h, float* __restrict__ asrc, float* __restrict__ adst,
    int N, int nwaves)
{
    int lane = threadIdx.x & 63;
    int wid = blockIdx.x * 4 + __builtin_amdgcn_readfirstlane(threadIdx.x >> 6);

    float w[K];
    #pragma unroll
    for (int k = 0; k < K; ++k) w[k] = W[k * 64 + lane];
    float as_c = att_s[lane];
    float ad_c = att_d[lane];

    for (int row = wid; row < N; row += nwaves) {
        float acc = 0.f;
        #pragma unroll
        for (int k = 0; k < 9; ++k) acc = fmaf(nf[row * 9 + k], w[k], acc);
        int b = batch[row];
        #pragma unroll
        for (int k = 0; k < 4; ++k) acc = fmaf(gf[b * 4 + k], w[9 + k], acc);

        h[(unsigned)row * 64u + (unsigned)lane] = __float2half(acc);
        float vs = acc * as_c;
        float vd = acc * ad_c;
        #pragma unroll
        for (int off = 8; off; off >>= 1) { vs += __shfl_xor(vs, off); vd += __shfl_xor(vd, off); }
        if ((lane & 15) == 0) {
            asrc[row * GAT_H + (lane >> 4)] = vs;
            adst[row * GAT_H + (lane >> 4)] = vd;
        }
    }
}

// ==================== binned CSR build ====================

__global__ __launch_bounds__(256) void zero_small(unsigned* __restrict__ bin_cnt,
                                                  unsigned* __restrict__ bin_fill)
{
    int t = threadIdx.x;
    bin_cnt[t] = 0; bin_cnt[t + 256] = 0;
    bin_fill[t] = 0; bin_fill[t + 256] = 0;
}

__global__ __launch_bounds__(256) void hist_bins(const int* __restrict__ dst,
                                                 unsigned* __restrict__ bin_cnt, int E)
{
    __shared__ unsigned lh[NBMAX];
    int t = threadIdx.x;
    lh[t] = 0; lh[t + 256] = 0;
    __syncthreads();
    for (int e = blockIdx.x * 256 + t; e < E; e += gridDim.x * 256)
        atomicAdd(&lh[((unsigned)dst[e]) >> 7], 1u);
    __syncthreads();
    unsigned v = lh[t];       if (v) atomicAdd(&bin_cnt[t], v);
    v = lh[t + 256];          if (v) atomicAdd(&bin_cnt[t + 256], v);
}

__global__ __launch_bounds__(256) void scan_bins(const unsigned* __restrict__ bin_cnt,
                                                 unsigned* __restrict__ bin_base,
                                                 int* __restrict__ indptr,
                                                 int nb, int N, int E)
{
    __shared__ unsigned buf[NBMAX];
    int t = threadIdx.x;
    buf[t] = (t < nb) ? bin_cnt[t] : 0u;
    buf[t + 256] = (t + 256 < nb) ? bin_cnt[t + 256] : 0u;
    __syncthreads();
    for (int off = 1; off < NBMAX; off <<= 1) {
        unsigned a = 0, b = 0;
        if (t >= off) a = buf[t - off];
        b = buf[t + 256 - off];
        __syncthreads();
        buf[t] += a; buf[t + 256] += b;
        __syncthreads();
    }
    if (t == 0) { bin_base[0] = 0; indptr[N] = E; }
    if (t < nb) bin_base[t + 1] = buf[t];
    if (t + 256 < nb) bin_base[t + 257] = buf[t + 256];
}

__global__ __launch_bounds__(256) void bin_scatter(const int* __restrict__ src,
                                                   const int* __restrict__ dst,
                                                   const unsigned* __restrict__ bin_base,
                                                   unsigned* __restrict__ bin_fill,
                                                   unsigned* __restrict__ binned, int E)
{
    __shared__ unsigned lh[NBMAX];
    __shared__ int goff[NBMAX];
    __shared__ unsigned sorted[CHUNK];
    int t = threadIdx.x;
    lh[t] = 0; lh[t + 256] = 0;
    __syncthreads();
    int e0 = blockIdx.x * CHUNK;

    unsigned pk[EPT]; int bn[EPT]; unsigned rk[EPT];
    #pragma unroll
    for (int i = 0; i < EPT; ++i) {
        int e = e0 + i * 256 + t;
        bn[i] = -1;
        if (e < E) {
            unsigned d = (unsigned)dst[e];
            pk[i] = (d << 16) | (unsigned)src[e];
            bn[i] = (int)(d >> 7);
            rk[i] = atomicAdd(&lh[bn[i]], 1u);
        }
    }
    __syncthreads();
    unsigned c0 = lh[t], c1 = lh[t + 256];   // own-bin counts (pre-scan)
    for (int off = 1; off < NBMAX; off <<= 1) {
        unsigned a = 0, b = 0;
        if (t >= off) a = lh[t - off];
        b = lh[t + 256 - off];
        __syncthreads();
        lh[t] += a; lh[t + 256] += b;
        __syncthreads();
    }
    unsigned x0 = lh[t] - c0, x1 = lh[t + 256] - c1;   // exclusive local bases
    if (c0) { unsigned g = atomicAdd(&bin_fill[t], c0);
              goff[t] = (int)(bin_base[t] + g) - (int)x0; }
    if (c1) { unsigned g = atomicAdd(&bin_fill[t + 256], c1);
              goff[t + 256] = (int)(bin_base[t + 256] + g) - (int)x1; }
    lh[t] = x0; lh[t + 256] = x1;            // own-entry overwrite only
    __syncthreads();
    #pragma unroll
    for (int i = 0; i < EPT; ++i)
        if (bn[i] >= 0) sorted[lh[bn[i]] + rk[i]] = pk[i];
    __syncthreads();
    int T = min(CHUNK, E - e0);
    for (int j = t; j < T; j += 256) {
        unsigned p = sorted[j];
        binned[goff[p >> 23] + j] = p;       // piecewise-contiguous runs
    }
}

__global__ __launch_bounds__(256) void bin_finalize(const unsigned* __restrict__ binned,
                                                    const unsigned* __restrict__ bin_base,
                                                    int* __restrict__ csr_src,
                                                    int* __restrict__ indptr, int N)
{
    __shared__ unsigned lh[DB];
    __shared__ unsigned fill[DB];
    int t = threadIdx.x, b = blockIdx.x;
    unsigned base = bin_base[b];
    unsigned cnt = bin_base[b + 1] - base;
    if (t < DB) lh[t] = 0;
    __syncthreads();
    for (unsigned i = t; i < cnt; i += 256)
        atomicAdd(&lh[(binned[base + i] >> 16) & (DB - 1)], 1u);
    __syncthreads();
    unsigned c0 = (t < DB) ? lh[t] : 0;
    for (int off = 1; off < DB; off <<= 1) {
        unsigned a = 0;
        if (t >= off && t < DB) a = lh[t - off];
        __syncthreads();
        if (t < DB) lh[t] += a;
        __syncthreads();
    }
    if (t < DB) {
        unsigned excl = lh[t] - c0;
        int d = b * DB + t;
        if (d < N) indptr[d] = (int)(base + excl);
        fill[t] = excl;
    }
    __syncthreads();
    for (unsigned i = t; i < cnt; i += 256) {
        unsigned p = binned[base + i];
        unsigned pos = atomicAdd(&fill[(p >> 16) & (DB - 1)], 1u);
        csr_src[base + pos] = (int)(p & 0xFFFFu);
    }
}

// ==================== fused aggregate + next-layer GEMM ====================
// Wave per node (grid-stride). Aggregate = proven R10 8-deep scalar-gather shape
// (fp16 h rows, per-lane asrc gather, scalar csr loads). Then the next layer's
// h row in-wave: W column in 64 VGPRs (NO LDS -> no occupancy collapse), dot
// product via readlane broadcasts with 4 parallel partial accumulators.
__global__ __launch_bounds__(256) void agg_gemm(
    const __half* __restrict__ hin, const float* __restrict__ asrcin,
    const float* __restrict__ adstin, const int* __restrict__ indptr,
    const int* __restrict__ csr_src, const float* __restrict__ bias,
    const float* __restrict__ Wn, const float* __restrict__ attsn,
    const float* __restrict__ attdn,
    __half* __restrict__ hout, float* __restrict__ asrcout, float* __restrict__ adstout,
    int N, int nwaves)
{
    int lane = threadIdx.x & 63;
    int wid = blockIdx.x * 4 + __builtin_amdgcn_readfirstlane(threadIdx.x >> 6);
    unsigned h16 = (unsigned)(lane >> 4);   // head

    float w[64];
    #pragma unroll
    for (int k = 0; k < 64; ++k) w[k] = Wn[k * 64 + lane];
    float bias_c = bias[lane];
    float as_c = attsn[lane];
    float ad_c = attdn[lane];

    for (int node = wid; node < N; node += nwaves) {
        int beg = __builtin_amdgcn_readfirstlane(indptr[node]);
        int end = __builtin_amdgcn_readfirstlane(indptr[node + 1]);
        unsigned un = (unsigned)node;

        float adst_n = adstin[un * 4u + h16];
        float p0 = __expf(lrelu(asrcin[un * 4u + h16] + adst_n));   // self loop
        float sacc = p0;
        float acc = __half2float(hin[un * 64u + (unsigned)lane]) * p0;

        int e = beg;
        for (; e + 8 <= end; e += 8) {
            int s[8]; float a[8], hv[8];
            #pragma unroll
            for (int i = 0; i < 8; ++i) s[i] = csr_src[e + i];           // scalar loads
            #pragma unroll
            for (int i = 0; i < 8; ++i) a[i] = asrcin[(unsigned)s[i] * 4u + h16];
            #pragma unroll
            for (int i = 0; i < 8; ++i)
                hv[i] = __half2float(hin[(unsigned)s[i] * 64u + (unsigned)lane]);
            #pragma unroll
            for (int i = 0; i < 8; ++i) {
                float p = __expf(lrelu(a[i] + adst_n));
                sacc += p;
                acc = fmaf(hv[i], p, acc);
            }
        }
        for (; e + 2 <= end; e += 2) {
            int s0 = csr_src[e], s1 = csr_src[e + 1];
            float a0 = asrcin[(unsigned)s0 * 4u + h16];
            float a1 = asrcin[(unsigned)s1 * 4u + h16];
            float h0 = __half2float(hin[(unsigned)s0 * 64u + (unsigned)lane]);
            float h1 = __half2float(hin[(unsigned)s1 * 64u + (unsigned)lane]);
            float pa = __expf(lrelu(a0 + adst_n));
            float pb = __expf(lrelu(a1 + adst_n));
            sacc += pa + pb;
            acc = fmaf(h0, pa, acc);
            acc = fmaf(h1, pb, acc);
        }
        if (e < end) {
            int s = csr_src[e];
            float p = __expf(lrelu(asrcin[(unsigned)s * 4u + h16] + adst_n));
            sacc += p;
            acc = fmaf(__half2float(hin[(unsigned)s * 64u + (unsigned)lane]), p, acc);
        }

        float o = fmaxf(acc / sacc + bias_c, 0.f);   // ReLU (layer 0/1 outputs)

        // next-layer GEMM row: 4 parallel partial sums of readlane(o,k)*w[k]
        float q0 = 0.f, q1 = 0.f, q2 = 0.f, q3 = 0.f;
        #pragma unroll
        for (int k = 0; k < 64; k += 4) {
            q0 = fmaf(__shfl(o, k + 0), w[k + 0], q0);
            q1 = fmaf(__shfl(o, k + 1), w[k + 1], q1);
            q2 = fmaf(__shfl(o, k + 2), w[k + 2], q2);
            q3 = fmaf(__shfl(o, k + 3), w[k + 3], q3);
        }
        float acc2 = (q0 + q1) + (q2 + q3);

        hout[un * 64u + (unsigned)lane] = __float2half(acc2);
        float vs = acc2 * as_c;
        float vd = acc2 * ad_c;
        #pragma unroll
        for (int off = 8; off; off >>= 1) { vs += __shfl_xor(vs, off); vd += __shfl_xor(vd, off); }
        if ((lane & 15) == 0) {
            asrcout[node * GAT_H + (lane >> 4)] = vs;
            adstout[node * GAT_H + (lane >> 4)] = vd;
        }
    }
}

// ---- final aggregate (layer 2): R11 16-deep shape, no activation, fp32 out ----
__global__ __launch_bounds__(256) void aggregate_final(
    const __half* __restrict__ h, const float* __restrict__ asrc,
    const float* __restrict__ adst, const int* __restrict__ indptr,
    const int* __restrict__ csr_src, const float* __restrict__ bias,
    float* __restrict__ xout, int N, int nwaves)
{
    int lane = threadIdx.x & 63;
    int wid = blockIdx.x * 4 + __builtin_amdgcn_readfirstlane(threadIdx.x >> 6);
    unsigned h16 = (unsigned)(lane >> 4);
    float bias_c = bias[lane];

    for (int node = wid; node < N; node += nwaves) {
        int beg = __builtin_amdgcn_readfirstlane(indptr[node]);
        int end = __builtin_amdgcn_readfirstlane(indptr[node + 1]);
        unsigned un = (unsigned)node;

        float adst_n = adst[un * 4u + h16];
        float p0 = __expf(lrelu(asrc[un * 4u + h16] + adst_n));
        float sacc = p0;
        float acc = __half2float(h[un * 64u + (unsigned)lane]) * p0;

        int e = beg;
        for (; e + 16 <= end; e += 16) {
            int s[16]; float a[16], hv[16];
            #pragma unroll
            for (int i = 0; i < 16; ++i) s[i] = csr_src[e + i];
            #pragma unroll
            for (int i = 0; i < 16; ++i) a[i] = asrc[(unsigned)s[i] * 4u + h16];
            #pragma unroll
            for (int i = 0; i < 16; ++i)
                hv[i] = __half2float(h[(unsigned)s[i] * 64u + (unsigned)lane]);
            #pragma unroll
            for (int i = 0; i < 16; ++i) {
                float p = __expf(lrelu(a[i] + adst_n));
                sacc += p;
                acc = fmaf(hv[i], p, acc);
            }
        }
        for (; e + 8 <= end; e += 8) {
            int s[8]; float a[8], hv[8];
            #pragma unroll
            for (int i = 0; i < 8; ++i) s[i] = csr_src[e + i];
            #pragma unroll
            for (int i = 0; i < 8; ++i) a[i] = asrc[(unsigned)s[i] * 4u + h16];
            #pragma unroll
            for (int i = 0; i < 8; ++i)
                hv[i] = __half2float(h[(unsigned)s[i] * 64u + (unsigned)lane]);
            #pragma unroll
            for (int i = 0; i < 8; ++i) {
                float p = __expf(lrelu(a[i] + adst_n));
                sacc += p;
                acc = fmaf(hv[i], p, acc);
            }
        }
        for (; e + 2 <= end; e += 2) {
            int s0 = csr_src[e], s1 = csr_src[e + 1];
            float a0 = asrc[(unsigned)s0 * 4u + h16];
            float a1 = asrc[(unsigned)s1 * 4u + h16];
            float h0 = __half2float(h[(unsigned)s0 * 64u + (unsigned)lane]);
            float h1 = __half2float(h[(unsigned)s1 * 64u + (unsigned)lane]);
            float pa = __expf(lrelu(a0 + adst_n));
            float pb = __expf(lrelu(a1 + adst_n));
            sacc += pa + pb;
            acc = fmaf(h0, pa, acc);
            acc = fmaf(h1, pb, acc);
        }
        if (e < end) {
            int s = csr_src[e];
            float p = __expf(lrelu(asrc[(unsigned)s * 4u + h16] + adst_n));
            sacc += p;
            acc = fmaf(__half2float(h[(unsigned)s * 64u + (unsigned)lane]), p, acc);
        }

        xout[un * 64u + (unsigned)lane] = acc / sacc + bias_c;
    }
}

// ---- fused scatter-mean pooling (batch_idx sorted -> binary search) + MLP head ----
__global__ void pool_mlp(const float* __restrict__ x, const int* __restrict__ batch, int N,
                         const float* __restrict__ W0, const float* __restrict__ b0,
                         const float* __restrict__ W1, const float* __restrict__ b1,
                         const float* __restrict__ W2, const float* __restrict__ b2,
                         const float* __restrict__ W3, const float* __restrict__ b3,
                         float* __restrict__ out)
{
    __shared__ int bounds[2];
    __shared__ float red[4][64];
    __shared__ float hb[64];
    int b = blockIdx.x, t = threadIdx.x;

    if (t < 2) {
        int target = b + t;
        int lo = 0, hi = N;
        while (lo < hi) {
            int mid = (lo + hi) >> 1;
            if (batch[mid] < target) lo = mid + 1; else hi = mid;
        }
        bounds[t] = lo;
    }
    __syncthreads();
    int beg = bounds[0], end = bounds[1];

    int c = t & 63, w = t >> 6;
    float sum = 0.f;
    for (int n = beg + w; n < end; n += 4) sum += x[(size_t)n * 64 + c];
    red[w][c] = sum;
    __syncthreads();
    if (t < 64) {
        float v = red[0][t] + red[1][t] + red[2][t] + red[3][t];
        float cb = fmaxf((float)(end - beg), 1.0f);
        hb[t] = v / cb;
    }
    __syncthreads();

    float v0 = 0.f;
    if (t < 64) {
        v0 = b0[t];
        for (int k = 0; k < 64; ++k) v0 = fmaf(hb[k], W0[k * 64 + t], v0);
        v0 = fmaxf(v0, 0.f);
    }
    __syncthreads(); if (t < 64) hb[t] = v0; __syncthreads();
    if (t < 64) {
        v0 = b1[t];
        for (int k = 0; k < 64; ++k) v0 = fmaf(hb[k], W1[k * 64 + t], v0);
        v0 = fmaxf(v0, 0.f);
    }
    __syncthreads(); if (t < 64) hb[t] = v0; __syncthreads();
    if (t < 64) {
        v0 = b2[t];
        for (int k = 0; k < 64; ++k) v0 = fmaf(hb[k], W2[k * 64 + t], v0);
        v0 = fmaxf(v0, 0.f);
    }
    __syncthreads(); if (t < 64) hb[t] = v0; __syncthreads();
    if (t < 64) {
        float r = hb[t] * W3[t];
        #pragma unroll
        for (int off = 32; off; off >>= 1) r += __shfl_xor(r, off);
        if (t == 0) out[b] = r + b3[0];
    }
}

extern "C" void kernel_launch(void* const* d_in, const int* in_sizes, int n_in,
                              void* d_out, int out_size, void* d_ws, size_t ws_size,
                              hipStream_t stream)
{
    const float* node_feats = (const float*)d_in[0];
    const float* glob       = (const float*)d_in[1];
    const int*   edge_index = (const int*)d_in[2];
    const int*   batch      = (const int*)d_in[3];
    const float* W[3]  = {(const float*)d_in[4],  (const float*)d_in[8],  (const float*)d_in[12]};
    const float* As[3] = {(const float*)d_in[5],  (const float*)d_in[9],  (const float*)d_in[13]};
    const float* Ad[3] = {(const float*)d_in[6],  (const float*)d_in[10], (const float*)d_in[14]};
    const float* Bi[3] = {(const float*)d_in[7],  (const float*)d_in[11], (const float*)d_in[15]};
    const float* mW0 = (const float*)d_in[16]; const float* mb0 = (const float*)d_in[17];
    const float* mW1 = (const float*)d_in[18]; const float* mb1 = (const float*)d_in[19];
    const float* mW2 = (const float*)d_in[20]; const float* mb2 = (const float*)d_in[21];
    const float* mW3 = (const float*)d_in[22]; const float* mb3 = (const float*)d_in[23];
    float* out = (float*)d_out;

    int N = in_sizes[0] / 9;
    int E = in_sizes[2] / 2;
    int B = in_sizes[1] / 4;
    const int* esrc = edge_index;
    const int* edst = edge_index + E;
    int nb = (N + DB - 1) / DB;

    // workspace layout
    char* ws = (char*)d_ws;
    size_t off = 0;
    auto alloc = [&](size_t bytes) -> void* {
        void* p = ws + off;
        off = (off + bytes + 255) & ~(size_t)255;
        return p;
    };
    __half*   hA       = (__half*)alloc((size_t)N * 64 * 2);
    __half*   hB       = (__half*)alloc((size_t)N * 64 * 2);
    float*    xfinal   = (float*)alloc((size_t)N * 64 * 4);
    float*    asA      = (float*)alloc((size_t)N * GAT_H * 4);
    float*    adA      = (float*)alloc((size_t)N * GAT_H * 4);
    float*    asB      = (float*)alloc((size_t)N * GAT_H * 4);
    float*    adB      = (float*)alloc((size_t)N * GAT_H * 4);
    int*      indptr   = (int*)alloc((size_t)(N + 1) * 4);
    int*      csr_src  = (int*)alloc((size_t)E * 4);
    unsigned* binned   = (unsigned*)alloc((size_t)E * 4);
    unsigned* bin_cnt  = (unsigned*)alloc(NBMAX * 4);
    unsigned* bin_base = (unsigned*)alloc((NBMAX + 1) * 4);
    unsigned* bin_fill = (unsigned*)alloc(NBMAX * 4);
    (void)ws_size;

    // CSR build (binned counting sort; once — shared by all 3 layers)
    zero_small<<<1, 256, 0, stream>>>(bin_cnt, bin_fill);
    hist_bins<<<400, 256, 0, stream>>>(edst, bin_cnt, E);
    scan_bins<<<1, 256, 0, stream>>>(bin_cnt, bin_base, indptr, nb, N, E);
    bin_scatter<<<(E + CHUNK - 1) / CHUNK, 256, 0, stream>>>(esrc, edst, bin_base, bin_fill,
                                                             binned, E);
    bin_finalize<<<nb, 256, 0, stream>>>(binned, bin_base, csr_src, indptr, N);

    // layer 0 GEMM (K=13, concat fused)
    gemm0_attn<13><<<1024, 256, 0, stream>>>(node_feats, glob, batch,
                                             W[0], As[0], Ad[0], hA, asA, adA, N, 4096);

    // layer-0 aggregate + layer-1 GEMM (fused, W in VGPRs)
    {
        int blocks = 3125;                       // 12500 waves, ~4 nodes/wave
        agg_gemm<<<blocks, 256, 0, stream>>>(hA, asA, adA, indptr, csr_src, Bi[0],
                                             W[1], As[1], Ad[1], hB, asB, adB,
                                             N, blocks * 4);
    }
    // layer-1 aggregate + layer-2 GEMM (fused)
    {
        int blocks = 3125;
        agg_gemm<<<blocks, 256, 0, stream>>>(hB, asB, adB, indptr, csr_src, Bi[1],
                                             W[2], As[2], Ad[2], hA, asA, adA,
                                             N, blocks * 4);
    }
    // layer-2 aggregate (no activation)
    {
        int blocks = 12500;                      // 50000 waves, 1 node/wave
        aggregate_final<<<blocks, 256, 0, stream>>>(hA, asA, adA, indptr, csr_src, Bi[2],
                                                    xfinal, N, blocks * 4);
    }

    // fused pooling + MLP head
    pool_mlp<<<B, 256, 0, stream>>>(xfinal, batch, N,
                                    mW0, mb0, mW1, mb1, mW2, mb2, mW3, mb3, out);
}

// Round 14
// 195.767 us; speedup vs baseline: 1.1830x; 1.0616x over previous
//
#include <hip/hip_runtime.h>
#include <hip/hip_fp16.h>

#define GAT_H 4
#define GAT_HC 64
#define NEG_SLOPE 0.2f
#define DB 128            // dsts per bin
#define NBMAX 512         // max bins (requires N <= 65536; here N=50000 -> 391)
#define CHUNK 4096        // edges per bin_scatter block
#define EPT 16            // edges per thread in bin_scatter
#define SLICES 128        // histogram slices (one per hist block)

__device__ __forceinline__ float lrelu(float x) { return x >= 0.f ? x : NEG_SLOPE * x; }

// ---- h = x@W [N,64] (fp16 out); fused per-node attention logits a_src,a_dst [N,4] ----
// Wave-per-row: W column in K VGPRs; x row wave-uniform -> scalar pipe loads.
template <int K, bool CONCAT>
__global__ __launch_bounds__(256) void gemm_attn(
    const float* __restrict__ x, const float* __restrict__ nf,
    const float* __restrict__ gf, const int* __restrict__ batch,
    const float* __restrict__ W,
    const float* __restrict__ att_s, const float* __restrict__ att_d,
    __half* __restrict__ h, float* __restrict__ asrc, float* __restrict__ adst,
    int N, int nwaves)
{
    int lane = threadIdx.x & 63;
    int wid = blockIdx.x * 4 + __builtin_amdgcn_readfirstlane(threadIdx.x >> 6);

    float w[K];
    #pragma unroll
    for (int k = 0; k < K; ++k) w[k] = W[k * 64 + lane];
    float as_c = att_s[lane];
    float ad_c = att_d[lane];

    for (int row = wid; row < N; row += nwaves) {
        float acc = 0.f;
        if (CONCAT) {
            #pragma unroll
            for (int k = 0; k < 9; ++k) acc = fmaf(nf[row * 9 + k], w[k], acc);
            int b = batch[row];
            #pragma unroll
            for (int k = 0; k < 4; ++k) acc = fmaf(gf[b * 4 + k], w[9 + k], acc);
        } else {
            #pragma unroll
            for (int k = 0; k < K; ++k) acc = fmaf(x[(size_t)row * K + k], w[k], acc);
        }
        h[(unsigned)row * 64u + (unsigned)lane] = __float2half(acc);
        float vs = acc * as_c;
        float vd = acc * ad_c;
        #pragma unroll
        for (int off = 8; off; off >>= 1) { vs += __shfl_xor(vs, off); vd += __shfl_xor(vd, off); }
        if ((lane & 15) == 0) {
            asrc[row * GAT_H + (lane >> 4)] = vs;
            adst[row * GAT_H + (lane >> 4)] = vd;
        }
    }
}

// ==================== binned CSR build ====================

// per-block histogram slices (no global atomics, no pre-zero kernel needed)
__global__ __launch_bounds__(256) void hist_bins(const int* __restrict__ dst,
                                                 unsigned* __restrict__ slices, int E)
{
    __shared__ unsigned lh[NBMAX];
    int t = threadIdx.x;
    lh[t] = 0; lh[t + 256] = 0;
    __syncthreads();
    for (int e = blockIdx.x * 256 + t; e < E; e += gridDim.x * 256)
        atomicAdd(&lh[((unsigned)dst[e]) >> 7], 1u);
    __syncthreads();
    unsigned* slice = slices + (size_t)blockIdx.x * NBMAX;
    slice[t] = lh[t];
    slice[t + 256] = lh[t + 256];
}

// sum slices -> scan -> bin_base; zero bin_fill; indptr[N]=E
__global__ __launch_bounds__(256) void scan_bins(const unsigned* __restrict__ slices,
                                                 unsigned* __restrict__ bin_base,
                                                 unsigned* __restrict__ bin_fill,
                                                 int* __restrict__ indptr,
                                                 int nslices, int N, int E)
{
    __shared__ unsigned buf[NBMAX];
    int t = threadIdx.x;
    unsigned s0 = 0, s1 = 0;
    for (int s = 0; s < nslices; ++s) {
        s0 += slices[(size_t)s * NBMAX + t];
        s1 += slices[(size_t)s * NBMAX + t + 256];
    }
    buf[t] = s0; buf[t + 256] = s1;
    bin_fill[t] = 0; bin_fill[t + 256] = 0;
    __syncthreads();
    for (int off = 1; off < NBMAX; off <<= 1) {
        unsigned a = 0, b = 0;
        if (t >= off) a = buf[t - off];
        b = buf[t + 256 - off];
        __syncthreads();
        buf[t] += a; buf[t + 256] += b;
        __syncthreads();
    }
    if (t == 0) { bin_base[0] = 0; indptr[N] = E; }
    bin_base[t + 1] = buf[t];
    bin_base[t + 257] = buf[t + 256];
}

// chunk-local LDS sort by bin, then run-coalesced scatter into bin segments.
// packed edge = (dst<<16)|src  (requires N <= 65536); bin = packed>>23.
__global__ __launch_bounds__(256) void bin_scatter(const int* __restrict__ src,
                                                   const int* __restrict__ dst,
                                                   const unsigned* __restrict__ bin_base,
                                                   unsigned* __restrict__ bin_fill,
                                                   unsigned* __restrict__ binned, int E)
{
    __shared__ unsigned lh[NBMAX];
    __shared__ int goff[NBMAX];
    __shared__ unsigned sorted[CHUNK];
    int t = threadIdx.x;
    lh[t] = 0; lh[t + 256] = 0;
    __syncthreads();
    int e0 = blockIdx.x * CHUNK;

    unsigned pk[EPT]; int bn[EPT]; unsigned rk[EPT];
    #pragma unroll
    for (int i = 0; i < EPT; ++i) {
        int e = e0 + i * 256 + t;
        bn[i] = -1;
        if (e < E) {
            unsigned d = (unsigned)dst[e];
            pk[i] = (d << 16) | (unsigned)src[e];
            bn[i] = (int)(d >> 7);
            rk[i] = atomicAdd(&lh[bn[i]], 1u);
        }
    }
    __syncthreads();
    unsigned c0 = lh[t], c1 = lh[t + 256];   // own-bin counts (pre-scan)
    for (int off = 1; off < NBMAX; off <<= 1) {
        unsigned a = 0, b = 0;
        if (t >= off) a = lh[t - off];
        b = lh[t + 256 - off];
        __syncthreads();
        lh[t] += a; lh[t + 256] += b;
        __syncthreads();
    }
    unsigned x0 = lh[t] - c0, x1 = lh[t + 256] - c1;   // exclusive local bases
    if (c0) { unsigned g = atomicAdd(&bin_fill[t], c0);
              goff[t] = (int)(bin_base[t] + g) - (int)x0; }
    if (c1) { unsigned g = atomicAdd(&bin_fill[t + 256], c1);
              goff[t + 256] = (int)(bin_base[t + 256] + g) - (int)x1; }
    lh[t] = x0; lh[t + 256] = x1;            // own-entry overwrite only
    __syncthreads();
    #pragma unroll
    for (int i = 0; i < EPT; ++i)
        if (bn[i] >= 0) sorted[lh[bn[i]] + rk[i]] = pk[i];
    __syncthreads();
    int T = min(CHUNK, E - e0);
    for (int j = t; j < T; j += 256) {
        unsigned p = sorted[j];
        binned[goff[p >> 23] + j] = p;       // piecewise-contiguous runs
    }
}

// block per bin; LDS counting-sort by dst_local -> final dst-sorted csr_src + indptr
__global__ __launch_bounds__(256) void bin_finalize(const unsigned* __restrict__ binned,
                                                    const unsigned* __restrict__ bin_base,
                                                    int* __restrict__ csr_src,
                                                    int* __restrict__ indptr, int N)
{
    __shared__ unsigned lh[DB];
    __shared__ unsigned fill[DB];
    int t = threadIdx.x, b = blockIdx.x;
    unsigned base = bin_base[b];
    unsigned cnt = bin_base[b + 1] - base;
    if (t < DB) lh[t] = 0;
    __syncthreads();
    for (unsigned i = t; i < cnt; i += 256)
        atomicAdd(&lh[(binned[base + i] >> 16) & (DB - 1)], 1u);
    __syncthreads();
    unsigned c0 = (t < DB) ? lh[t] : 0;
    for (int off = 1; off < DB; off <<= 1) {
        unsigned a = 0;
        if (t >= off && t < DB) a = lh[t - off];
        __syncthreads();
        if (t < DB) lh[t] += a;
        __syncthreads();
    }
    if (t < DB) {
        unsigned excl = lh[t] - c0;
        int d = b * DB + t;
        if (d < N) indptr[d] = (int)(base + excl);
        fill[t] = excl;
    }
    __syncthreads();
    for (unsigned i = t; i < cnt; i += 256) {
        unsigned p = binned[base + i];
        unsigned pos = atomicAdd(&fill[(p >> 16) & (DB - 1)], 1u);
        csr_src[base + pos] = (int)(p & 0xFFFFu);
    }
}

// ==================== aggregation v2: 8-edge x 8-channel-octet mapping ====================
// Wave per node. lane = eslot*8 + c8 (eslot = edge slot 0..7, c8 = channel octet 0..7;
// head = c8>>1). Per 8 edges: 1 csr gather + 1 asrc gather + 1 h dwordx4 (8 rows per
// instruction) + ONE exp instruction covering 8 edges x 4 heads. Fold = 3 shfl steps
// over 9 regs. Virtual edge 0 = self loop.
template <bool RELU>
__global__ __launch_bounds__(256) void aggregate8(
    const __half* __restrict__ h, const float* __restrict__ asrc,
    const float* __restrict__ adst, const int* __restrict__ indptr,
    const int* __restrict__ csr_src, const float* __restrict__ bias,
    float* __restrict__ xout, int N, int nwaves)
{
    int lane = threadIdx.x & 63;
    int eslot = lane >> 3;                   // 0..7
    unsigned c8 = (unsigned)(lane & 7);      // channel octet: channels c8*8..c8*8+7
    unsigned head = c8 >> 1;
    int wid = blockIdx.x * 4 + __builtin_amdgcn_readfirstlane(threadIdx.x >> 6);

    float4 bias0 = *reinterpret_cast<const float4*>(bias + c8 * 8u);
    float4 bias1 = *reinterpret_cast<const float4*>(bias + c8 * 8u + 4u);

    for (int node = wid; node < N; node += nwaves) {
        int beg = __builtin_amdgcn_readfirstlane(indptr[node]);
        int end = __builtin_amdgcn_readfirstlane(indptr[node + 1]);
        int total = (end - beg) + 1;         // virtual idx 0 = self loop

        float adst_n = adst[(unsigned)node * 4u + head];
        float sacc = 0.f;
        float acc[8];
        #pragma unroll
        for (int j = 0; j < 8; ++j) acc[j] = 0.f;

        int g = 0;
        // staged x2: 16 virtual edges per iteration, 6 independent VMEM in flight
        for (; g + 16 <= total; g += 16) {
            int i0 = g + eslot;
            int i1 = g + 8 + eslot;
            int s0 = (i0 == 0) ? node : csr_src[beg + i0 - 1];
            int s1 = csr_src[beg + i1 - 1];          // i1 >= 8 > 0
            float a0 = asrc[(unsigned)s0 * 4u + head];
            float a1 = asrc[(unsigned)s1 * 4u + head];
            uint4 hv0 = *reinterpret_cast<const uint4*>(h + (unsigned)s0 * 64u + c8 * 8u);
            uint4 hv1 = *reinterpret_cast<const uint4*>(h + (unsigned)s1 * 64u + c8 * 8u);
            float p0 = __expf(lrelu(a0 + adst_n));
            float p1 = __expf(lrelu(a1 + adst_n));
            sacc += p0 + p1;
            const __half2* q0 = reinterpret_cast<const __half2*>(&hv0);
            const __half2* q1 = reinterpret_cast<const __half2*>(&hv1);
            #pragma unroll
            for (int j = 0; j < 4; ++j) {
                float2 f0 = __half22float2(q0[j]);
                float2 f1 = __half22float2(q1[j]);
                acc[2 * j]     = fmaf(f0.x, p0, acc[2 * j]);
                acc[2 * j + 1] = fmaf(f0.y, p0, acc[2 * j + 1]);
                acc[2 * j]     = fmaf(f1.x, p1, acc[2 * j]);
                acc[2 * j + 1] = fmaf(f1.y, p1, acc[2 * j + 1]);
            }
        }
        for (; g < total; g += 8) {
            int idx = g + eslot;
            if (idx < total) {
                int s = (idx == 0) ? node : csr_src[beg + idx - 1];
                float a = asrc[(unsigned)s * 4u + head];
                uint4 hv = *reinterpret_cast<const uint4*>(h + (unsigned)s * 64u + c8 * 8u);
                float p = __expf(lrelu(a + adst_n));
                sacc += p;
                const __half2* q = reinterpret_cast<const __half2*>(&hv);
                #pragma unroll
                for (int j = 0; j < 4; ++j) {
                    float2 f = __half22float2(q[j]);
                    acc[2 * j]     = fmaf(f.x, p, acc[2 * j]);
                    acc[2 * j + 1] = fmaf(f.y, p, acc[2 * j + 1]);
                }
            }
        }

        // fold the 8 edge slots (lane bits 3..5)
        #pragma unroll
        for (int off = 8; off <= 32; off <<= 1) {
            sacc += __shfl_xor(sacc, off);
            #pragma unroll
            for (int j = 0; j < 8; ++j) acc[j] += __shfl_xor(acc[j], off);
        }

        if (eslot == 0) {                    // lanes 0..7 write channels c8*8..c8*8+7
            float inv = 1.0f / sacc;
            float4 o0, o1;
            o0.x = fmaf(acc[0], inv, bias0.x);
            o0.y = fmaf(acc[1], inv, bias0.y);
            o0.z = fmaf(acc[2], inv, bias0.z);
            o0.w = fmaf(acc[3], inv, bias0.w);
            o1.x = fmaf(acc[4], inv, bias1.x);
            o1.y = fmaf(acc[5], inv, bias1.y);
            o1.z = fmaf(acc[6], inv, bias1.z);
            o1.w = fmaf(acc[7], inv, bias1.w);
            if (RELU) {
                o0.x = fmaxf(o0.x, 0.f); o0.y = fmaxf(o0.y, 0.f);
                o0.z = fmaxf(o0.z, 0.f); o0.w = fmaxf(o0.w, 0.f);
                o1.x = fmaxf(o1.x, 0.f); o1.y = fmaxf(o1.y, 0.f);
                o1.z = fmaxf(o1.z, 0.f); o1.w = fmaxf(o1.w, 0.f);
            }
            float* op = xout + (unsigned)node * 64u + c8 * 8u;
            *reinterpret_cast<float4*>(op) = o0;
            *reinterpret_cast<float4*>(op + 4) = o1;
        }
    }
}

// ==================== aggregation v1 (R11 control, layer 2) ====================
template <bool RELU>
__global__ __launch_bounds__(256) void aggregate(
    const __half* __restrict__ h, const float* __restrict__ asrc,
    const float* __restrict__ adst, const int* __restrict__ indptr,
    const int* __restrict__ csr_src, const float* __restrict__ bias,
    float* __restrict__ xout, int N, int nwaves)
{
    int lane = threadIdx.x & 63;
    int wid = blockIdx.x * 4 + __builtin_amdgcn_readfirstlane(threadIdx.x >> 6);
    unsigned h16 = (unsigned)(lane >> 4);   // head
    float bias_c = bias[lane];

    for (int node = wid; node < N; node += nwaves) {
        int beg = __builtin_amdgcn_readfirstlane(indptr[node]);
        int end = __builtin_amdgcn_readfirstlane(indptr[node + 1]);
        unsigned un = (unsigned)node;

        float adst_n = adst[un * 4u + h16];
        float p0 = __expf(lrelu(asrc[un * 4u + h16] + adst_n));   // self loop
        float sacc = p0;
        float acc = __half2float(h[un * 64u + (unsigned)lane]) * p0;

        int e = beg;
        for (; e + 16 <= end; e += 16) {
            int s[16]; float a[16], hv[16];
            #pragma unroll
            for (int i = 0; i < 16; ++i) s[i] = csr_src[e + i];
            #pragma unroll
            for (int i = 0; i < 16; ++i) a[i] = asrc[(unsigned)s[i] * 4u + h16];
            #pragma unroll
            for (int i = 0; i < 16; ++i)
                hv[i] = __half2float(h[(unsigned)s[i] * 64u + (unsigned)lane]);
            #pragma unroll
            for (int i = 0; i < 16; ++i) {
                float p = __expf(lrelu(a[i] + adst_n));
                sacc += p;
                acc = fmaf(hv[i], p, acc);
            }
        }
        for (; e + 8 <= end; e += 8) {
            int s[8]; float a[8], hv[8];
            #pragma unroll
            for (int i = 0; i < 8; ++i) s[i] = csr_src[e + i];
            #pragma unroll
            for (int i = 0; i < 8; ++i) a[i] = asrc[(unsigned)s[i] * 4u + h16];
            #pragma unroll
            for (int i = 0; i < 8; ++i)
                hv[i] = __half2float(h[(unsigned)s[i] * 64u + (unsigned)lane]);
            #pragma unroll
            for (int i = 0; i < 8; ++i) {
                float p = __expf(lrelu(a[i] + adst_n));
                sacc += p;
                acc = fmaf(hv[i], p, acc);
            }
        }
        for (; e + 2 <= end; e += 2) {
            int s0 = csr_src[e], s1 = csr_src[e + 1];
            float a0 = asrc[(unsigned)s0 * 4u + h16];
            float a1 = asrc[(unsigned)s1 * 4u + h16];
            float h0 = __half2float(h[(unsigned)s0 * 64u + (unsigned)lane]);
            float h1 = __half2float(h[(unsigned)s1 * 64u + (unsigned)lane]);
            float pa = __expf(lrelu(a0 + adst_n));
            float pb = __expf(lrelu(a1 + adst_n));
            sacc += pa + pb;
            acc = fmaf(h0, pa, acc);
            acc = fmaf(h1, pb, acc);
        }
        if (e < end) {
            int s = csr_src[e];
            float p = __expf(lrelu(asrc[(unsigned)s * 4u + h16] + adst_n));
            sacc += p;
            acc = fmaf(__half2float(h[(unsigned)s * 64u + (unsigned)lane]), p, acc);
        }

        float o = acc / sacc + bias_c;
        if (RELU) o = fmaxf(o, 0.f);
        xout[un * 64u + (unsigned)lane] = o;
    }
}

// ---- fused scatter-mean pooling (batch_idx sorted -> binary search) + MLP head ----
__global__ void pool_mlp(const float* __restrict__ x, const int* __restrict__ batch, int N,
                         const float* __restrict__ W0, const float* __restrict__ b0,
                         const float* __restrict__ W1, const float* __restrict__ b1,
                         const float* __restrict__ W2, const float* __restrict__ b2,
                         const float* __restrict__ W3, const float* __restrict__ b3,
                         float* __restrict__ out)
{
    __shared__ int bounds[2];
    __shared__ float red[4][64];
    __shared__ float hb[64];
    int b = blockIdx.x, t = threadIdx.x;

    if (t < 2) {
        int target = b + t;
        int lo = 0, hi = N;
        while (lo < hi) {
            int mid = (lo + hi) >> 1;
            if (batch[mid] < target) lo = mid + 1; else hi = mid;
        }
        bounds[t] = lo;
    }
    __syncthreads();
    int beg = bounds[0], end = bounds[1];

    int c = t & 63, w = t >> 6;
    float sum = 0.f;
    for (int n = beg + w; n < end; n += 4) sum += x[(size_t)n * 64 + c];
    red[w][c] = sum;
    __syncthreads();
    if (t < 64) {
        float v = red[0][t] + red[1][t] + red[2][t] + red[3][t];
        float cb = fmaxf((float)(end - beg), 1.0f);
        hb[t] = v / cb;
    }
    __syncthreads();

    float v0 = 0.f;
    if (t < 64) {
        v0 = b0[t];
        for (int k = 0; k < 64; ++k) v0 = fmaf(hb[k], W0[k * 64 + t], v0);
        v0 = fmaxf(v0, 0.f);
    }
    __syncthreads(); if (t < 64) hb[t] = v0; __syncthreads();
    if (t < 64) {
        v0 = b1[t];
        for (int k = 0; k < 64; ++k) v0 = fmaf(hb[k], W1[k * 64 + t], v0);
        v0 = fmaxf(v0, 0.f);
    }
    __syncthreads(); if (t < 64) hb[t] = v0; __syncthreads();
    if (t < 64) {
        v0 = b2[t];
        for (int k = 0; k < 64; ++k) v0 = fmaf(hb[k], W2[k * 64 + t], v0);
        v0 = fmaxf(v0, 0.f);
    }
    __syncthreads(); if (t < 64) hb[t] = v0; __syncthreads();
    if (t < 64) {
        float r = hb[t] * W3[t];
        #pragma unroll
        for (int off = 32; off; off >>= 1) r += __shfl_xor(r, off);
        if (t == 0) out[b] = r + b3[0];
    }
}

extern "C" void kernel_launch(void* const* d_in, const int* in_sizes, int n_in,
                              void* d_out, int out_size, void* d_ws, size_t ws_size,
                              hipStream_t stream)
{
    const float* node_feats = (const float*)d_in[0];
    const float* glob       = (const float*)d_in[1];
    const int*   edge_index = (const int*)d_in[2];
    const int*   batch      = (const int*)d_in[3];
    const float* W[3]  = {(const float*)d_in[4],  (const float*)d_in[8],  (const float*)d_in[12]};
    const float* As[3] = {(const float*)d_in[5],  (const float*)d_in[9],  (const float*)d_in[13]};
    const float* Ad[3] = {(const float*)d_in[6],  (const float*)d_in[10], (const float*)d_in[14]};
    const float* Bi[3] = {(const float*)d_in[7],  (const float*)d_in[11], (const float*)d_in[15]};
    const float* mW0 = (const float*)d_in[16]; const float* mb0 = (const float*)d_in[17];
    const float* mW1 = (const float*)d_in[18]; const float* mb1 = (const float*)d_in[19];
    const float* mW2 = (const float*)d_in[20]; const float* mb2 = (const float*)d_in[21];
    const float* mW3 = (const float*)d_in[22]; const float* mb3 = (const float*)d_in[23];
    float* out = (float*)d_out;

    int N = in_sizes[0] / 9;
    int E = in_sizes[2] / 2;
    int B = in_sizes[1] / 4;
    const int* esrc = edge_index;
    const int* edst = edge_index + E;
    int nb = (N + DB - 1) / DB;

    // workspace layout
    char* ws = (char*)d_ws;
    size_t off = 0;
    auto alloc = [&](size_t bytes) -> void* {
        void* p = ws + off;
        off = (off + bytes + 255) & ~(size_t)255;
        return p;
    };
    __half*   hbuf     = (__half*)alloc((size_t)N * 64 * 2);
    float*    xbuf     = (float*)alloc((size_t)N * 64 * 4);
    float*    asrc     = (float*)alloc((size_t)N * GAT_H * 4);
    float*    adst     = (float*)alloc((size_t)N * GAT_H * 4);
    int*      indptr   = (int*)alloc((size_t)(N + 1) * 4);
    int*      csr_src  = (int*)alloc((size_t)E * 4);
    unsigned* binned   = (unsigned*)alloc((size_t)E * 4);
    unsigned* slices   = (unsigned*)alloc((size_t)SLICES * NBMAX * 4);
    unsigned* bin_base = (unsigned*)alloc((NBMAX + 1) * 4);
    unsigned* bin_fill = (unsigned*)alloc(NBMAX * 4);
    (void)ws_size;

    // CSR build (binned counting sort; once — shared by all 3 layers)
    hist_bins<<<SLICES, 256, 0, stream>>>(edst, slices, E);
    scan_bins<<<1, 256, 0, stream>>>(slices, bin_base, bin_fill, indptr, SLICES, N, E);
    bin_scatter<<<(E + CHUNK - 1) / CHUNK, 256, 0, stream>>>(esrc, edst, bin_base, bin_fill,
                                                             binned, E);
    bin_finalize<<<nb, 256, 0, stream>>>(binned, bin_base, csr_src, indptr, N);

    const int gemmBlocks = 1024;
    const int aggBlocks = 12500;    // 50000 waves -> 1 node per wave
    // layer 0 (K=13, concat fused)
    gemm_attn<13, true><<<gemmBlocks, 256, 0, stream>>>(nullptr, node_feats, glob, batch,
                                                        W[0], As[0], Ad[0], hbuf, asrc, adst,
                                                        N, gemmBlocks * 4);
    aggregate8<true><<<aggBlocks, 256, 0, stream>>>(hbuf, asrc, adst, indptr, csr_src, Bi[0],
                                                    xbuf, N, aggBlocks * 4);
    // layer 1 (K=64)
    gemm_attn<64, false><<<gemmBlocks, 256, 0, stream>>>(xbuf, nullptr, nullptr, nullptr,
                                                         W[1], As[1], Ad[1], hbuf, asrc, adst,
                                                         N, gemmBlocks * 4);
    aggregate8<true><<<aggBlocks, 256, 0, stream>>>(hbuf, asrc, adst, indptr, csr_src, Bi[1],
                                                    xbuf, N, aggBlocks * 4);
    // layer 2 (K=64, no act) — control: R11 16-deep aggregate for in-profile A/B
    gemm_attn<64, false><<<gemmBlocks, 256, 0, stream>>>(xbuf, nullptr, nullptr, nullptr,
                                                         W[2], As[2], Ad[2], hbuf, asrc, adst,
                                                         N, gemmBlocks * 4);
    aggregate<false><<<aggBlocks, 256, 0, stream>>>(hbuf, asrc, adst, indptr, csr_src, Bi[2],
                                                    xbuf, N, aggBlocks * 4);

    // fused pooling + MLP head
    pool_mlp<<<B, 256, 0, stream>>>(xbuf, batch, N,
                                    mW0, mb0, mW1, mb1, mW2, mb2, mW3, mb3, out);
}

// Round 15
// 194.539 us; speedup vs baseline: 1.1904x; 1.0063x over previous
//
#include <hip/hip_runtime.h>
#include <hip/hip_fp16.h>

#define GAT_H 4
#define GAT_HC 64
#define NEG_SLOPE 0.2f
#define LOG2E 1.4426950408889634f
#define DB 128            // dsts per bin
#define NBMAX 512         // max bins (requires N <= 65536; here N=50000 -> 391)
#define CHUNK 4096        // edges per bin_scatter block
#define EPT 16            // edges per thread in bin_scatter
#define SLICES 128        // histogram slices (one per hist block)

__device__ __forceinline__ float lrelu(float x) { return x >= 0.f ? x : NEG_SLOPE * x; }

// ---- h = x@W [N,64] (fp16 out); fused per-node attention logits a_src,a_dst [N,4] ----
// Logits PRE-SCALED by log2e so the aggregate uses exp2 directly.
template <int K, bool CONCAT>
__global__ __launch_bounds__(256) void gemm_attn(
    const float* __restrict__ x, const float* __restrict__ nf,
    const float* __restrict__ gf, const int* __restrict__ batch,
    const float* __restrict__ W,
    const float* __restrict__ att_s, const float* __restrict__ att_d,
    __half* __restrict__ h, float* __restrict__ asrc, float* __restrict__ adst,
    int N, int nwaves)
{
    int lane = threadIdx.x & 63;
    int wid = blockIdx.x * 4 + __builtin_amdgcn_readfirstlane(threadIdx.x >> 6);

    float w[K];
    #pragma unroll
    for (int k = 0; k < K; ++k) w[k] = W[k * 64 + lane];
    float as_c = att_s[lane] * LOG2E;
    float ad_c = att_d[lane] * LOG2E;

    for (int row = wid; row < N; row += nwaves) {
        float acc = 0.f;
        if (CONCAT) {
            #pragma unroll
            for (int k = 0; k < 9; ++k) acc = fmaf(nf[row * 9 + k], w[k], acc);
            int b = batch[row];
            #pragma unroll
            for (int k = 0; k < 4; ++k) acc = fmaf(gf[b * 4 + k], w[9 + k], acc);
        } else {
            #pragma unroll
            for (int k = 0; k < K; ++k) acc = fmaf(x[(size_t)row * K + k], w[k], acc);
        }
        h[(unsigned)row * 64u + (unsigned)lane] = __float2half(acc);
        float vs = acc * as_c;
        float vd = acc * ad_c;
        #pragma unroll
        for (int off = 8; off; off >>= 1) { vs += __shfl_xor(vs, off); vd += __shfl_xor(vd, off); }
        if ((lane & 15) == 0) {
            asrc[row * GAT_H + (lane >> 4)] = vs;
            adst[row * GAT_H + (lane >> 4)] = vd;
        }
    }
}

// ==================== binned CSR build ====================

// per-block histogram slices (no global atomics, no pre-zero kernel needed)
__global__ __launch_bounds__(256) void hist_bins(const int* __restrict__ dst,
                                                 unsigned* __restrict__ slices, int E)
{
    __shared__ unsigned lh[NBMAX];
    int t = threadIdx.x;
    lh[t] = 0; lh[t + 256] = 0;
    __syncthreads();
    for (int e = blockIdx.x * 256 + t; e < E; e += gridDim.x * 256)
        atomicAdd(&lh[((unsigned)dst[e]) >> 7], 1u);
    __syncthreads();
    unsigned* slice = slices + (size_t)blockIdx.x * NBMAX;
    slice[t] = lh[t];
    slice[t + 256] = lh[t + 256];
}

// sum slices -> scan -> bin_base; zero bin_fill; indptr[N]=E
__global__ __launch_bounds__(256) void scan_bins(const unsigned* __restrict__ slices,
                                                 unsigned* __restrict__ bin_base,
                                                 unsigned* __restrict__ bin_fill,
                                                 int* __restrict__ indptr,
                                                 int nslices, int N, int E)
{
    __shared__ unsigned buf[NBMAX];
    int t = threadIdx.x;
    unsigned s0 = 0, s1 = 0;
    for (int s = 0; s < nslices; ++s) {
        s0 += slices[(size_t)s * NBMAX + t];
        s1 += slices[(size_t)s * NBMAX + t + 256];
    }
    buf[t] = s0; buf[t + 256] = s1;
    bin_fill[t] = 0; bin_fill[t + 256] = 0;
    __syncthreads();
    for (int off = 1; off < NBMAX; off <<= 1) {
        unsigned a = 0, b = 0;
        if (t >= off) a = buf[t - off];
        b = buf[t + 256 - off];
        __syncthreads();
        buf[t] += a; buf[t + 256] += b;
        __syncthreads();
    }
    if (t == 0) { bin_base[0] = 0; indptr[N] = E; }
    bin_base[t + 1] = buf[t];
    bin_base[t + 257] = buf[t + 256];
}

// chunk-local LDS sort by bin, then run-coalesced scatter into bin segments.
// packed edge = (dst<<16)|src  (requires N <= 65536); bin = packed>>23.
__global__ __launch_bounds__(256) void bin_scatter(const int* __restrict__ src,
                                                   const int* __restrict__ dst,
                                                   const unsigned* __restrict__ bin_base,
                                                   unsigned* __restrict__ bin_fill,
                                                   unsigned* __restrict__ binned, int E)
{
    __shared__ unsigned lh[NBMAX];
    __shared__ int goff[NBMAX];
    __shared__ unsigned sorted[CHUNK];
    int t = threadIdx.x;
    lh[t] = 0; lh[t + 256] = 0;
    __syncthreads();
    int e0 = blockIdx.x * CHUNK;

    unsigned pk[EPT]; int bn[EPT]; unsigned rk[EPT];
    #pragma unroll
    for (int i = 0; i < EPT; ++i) {
        int e = e0 + i * 256 + t;
        bn[i] = -1;
        if (e < E) {
            unsigned d = (unsigned)dst[e];
            pk[i] = (d << 16) | (unsigned)src[e];
            bn[i] = (int)(d >> 7);
            rk[i] = atomicAdd(&lh[bn[i]], 1u);
        }
    }
    __syncthreads();
    unsigned c0 = lh[t], c1 = lh[t + 256];   // own-bin counts (pre-scan)
    for (int off = 1; off < NBMAX; off <<= 1) {
        unsigned a = 0, b = 0;
        if (t >= off) a = lh[t - off];
        b = lh[t + 256 - off];
        __syncthreads();
        lh[t] += a; lh[t + 256] += b;
        __syncthreads();
    }
    unsigned x0 = lh[t] - c0, x1 = lh[t + 256] - c1;   // exclusive local bases
    if (c0) { unsigned g = atomicAdd(&bin_fill[t], c0);
              goff[t] = (int)(bin_base[t] + g) - (int)x0; }
    if (c1) { unsigned g = atomicAdd(&bin_fill[t + 256], c1);
              goff[t + 256] = (int)(bin_base[t + 256] + g) - (int)x1; }
    lh[t] = x0; lh[t + 256] = x1;            // own-entry overwrite only
    __syncthreads();
    #pragma unroll
    for (int i = 0; i < EPT; ++i)
        if (bn[i] >= 0) sorted[lh[bn[i]] + rk[i]] = pk[i];
    __syncthreads();
    int T = min(CHUNK, E - e0);
    for (int j = t; j < T; j += 256) {
        unsigned p = sorted[j];
        binned[goff[p >> 23] + j] = p;       // piecewise-contiguous runs
    }
}

// block per bin; LDS counting-sort by dst_local -> final dst-sorted csr_src + indptr
__global__ __launch_bounds__(256) void bin_finalize(const unsigned* __restrict__ binned,
                                                    const unsigned* __restrict__ bin_base,
                                                    int* __restrict__ csr_src,
                                                    int* __restrict__ indptr, int N, int E)
{
    __shared__ unsigned lh[DB];
    __shared__ unsigned fill[DB];
    int t = threadIdx.x, b = blockIdx.x;
    if (b == 0 && t < 16) csr_src[E + t] = 0;   // zero pad for aggregate prefetch
    unsigned base = bin_base[b];
    unsigned cnt = bin_base[b + 1] - base;
    if (t < DB) lh[t] = 0;
    __syncthreads();
    for (unsigned i = t; i < cnt; i += 256)
        atomicAdd(&lh[(binned[base + i] >> 16) & (DB - 1)], 1u);
    __syncthreads();
    unsigned c0 = (t < DB) ? lh[t] : 0;
    for (int off = 1; off < DB; off <<= 1) {
        unsigned a = 0;
        if (t >= off && t < DB) a = lh[t - off];
        __syncthreads();
        if (t < DB) lh[t] += a;
        __syncthreads();
    }
    if (t < DB) {
        unsigned excl = lh[t] - c0;
        int d = b * DB + t;
        if (d < N) indptr[d] = (int)(base + excl);
        fill[t] = excl;
    }
    __syncthreads();
    for (unsigned i = t; i < cnt; i += 256) {
        unsigned p = binned[base + i];
        unsigned pos = atomicAdd(&fill[(p >> 16) & (DB - 1)], 1u);
        csr_src[base + pos] = (int)(p & 0xFFFFu);
    }
}

// ==================== aggregation v3: batched-p + R11 h-path ====================
// Wave per node. p-path: lanes (el=lane>>2, hp=lane&3) compute 16 edges' exp2
// in ~6 wave-instrs + xor-tree; per-edge p reaches fma lanes via ds_bpermute
// (LDS pipe). h-path: UNCHANGED R11 shape — scalar csr loads, SALU row base,
// same-row 128B gathers, 8-deep batches. Invalid slots have p=0 (safe fmas).
template <bool RELU>
__global__ __launch_bounds__(256) void aggregate3(
    const __half* __restrict__ h, const float* __restrict__ asrc,
    const float* __restrict__ adst, const int* __restrict__ indptr,
    const int* __restrict__ csr_src, const float* __restrict__ bias,
    float* __restrict__ xout, int N, int nwaves)
{
    int lane = threadIdx.x & 63;
    int wid = blockIdx.x * 4 + __builtin_amdgcn_readfirstlane(threadIdx.x >> 6);
    int h16 = lane >> 4;                 // head for h/fma path
    unsigned hp = (unsigned)(lane & 3);  // head for p path
    int el = lane >> 2;                  // edge slot 0..15 for p path
    float bias_c = bias[lane];

    for (int node = wid; node < N; node += nwaves) {
        int beg = __builtin_amdgcn_readfirstlane(indptr[node]);
        int end = __builtin_amdgcn_readfirstlane(indptr[node + 1]);
        int cnt = end - beg;
        unsigned un = (unsigned)node;

        // self loop (h16 mapping, logits pre-scaled by log2e)
        float p0 = exp2f(lrelu(asrc[un * 4u + (unsigned)h16] + adst[un * 4u + (unsigned)h16]));
        float acc = __half2float(h[un * 64u + (unsigned)lane]) * p0;
        float adst_p = adst[un * 4u + hp];
        float sacc_p = 0.f;

        for (int g = 0; g < cnt; g += 16) {
            // ---- batched p for 16 edges (lanes = edge-slot x head) ----
            int idx = beg + g + el;                       // csr padded, safe
            float a = (g + el < cnt) ? asrc[(unsigned)csr_src[idx] * 4u + hp]
                                     : -INFINITY;
            float p = exp2f(lrelu(a + adst_p));           // p=0 for invalid
            float ps = p;
            ps += __shfl_xor(ps, 4);
            ps += __shfl_xor(ps, 8);
            ps += __shfl_xor(ps, 16);
            ps += __shfl_xor(ps, 32);
            sacc_p += ps;                                 // group sum per head (lane&3)

            // ---- h-path: two sub-batches of 8 (scalar csr, same-row gathers) ----
            #pragma unroll
            for (int sb = 0; sb < 2; ++sb) {
                if (g + sb * 8 >= cnt) break;             // uniform skip
                int base = beg + g + sb * 8;
                __half hv[8]; float pe[8];
                #pragma unroll
                for (int i = 0; i < 8; ++i) {
                    int s = csr_src[base + i];            // scalar load (pad-safe)
                    hv[i] = h[(unsigned)s * 64u + (unsigned)lane];
                    pe[i] = __shfl(p, (sb * 8 + i) * 4 + h16);
                }
                #pragma unroll
                for (int i = 0; i < 8; ++i)
                    acc = fmaf(__half2float(hv[i]), pe[i], acc);  // invalid: pe=0
            }
        }

        float sacc = p0 + __shfl(sacc_p, h16);
        float o = acc / sacc + bias_c;
        if (RELU) o = fmaxf(o, 0.f);
        xout[un * 64u + (unsigned)lane] = o;
    }
}

// ---- fused scatter-mean pooling (batch_idx sorted -> binary search) + MLP head ----
__global__ void pool_mlp(const float* __restrict__ x, const int* __restrict__ batch, int N,
                         const float* __restrict__ W0, const float* __restrict__ b0,
                         const float* __restrict__ W1, const float* __restrict__ b1,
                         const float* __restrict__ W2, const float* __restrict__ b2,
                         const float* __restrict__ W3, const float* __restrict__ b3,
                         float* __restrict__ out)
{
    __shared__ int bounds[2];
    __shared__ float red[4][64];
    __shared__ float hb[64];
    int b = blockIdx.x, t = threadIdx.x;

    if (t < 2) {
        int target = b + t;
        int lo = 0, hi = N;
        while (lo < hi) {
            int mid = (lo + hi) >> 1;
            if (batch[mid] < target) lo = mid + 1; else hi = mid;
        }
        bounds[t] = lo;
    }
    __syncthreads();
    int beg = bounds[0], end = bounds[1];

    int c = t & 63, w = t >> 6;
    float sum = 0.f;
    for (int n = beg + w; n < end; n += 4) sum += x[(size_t)n * 64 + c];
    red[w][c] = sum;
    __syncthreads();
    if (t < 64) {
        float v = red[0][t] + red[1][t] + red[2][t] + red[3][t];
        float cb = fmaxf((float)(end - beg), 1.0f);
        hb[t] = v / cb;
    }
    __syncthreads();

    float v0 = 0.f;
    if (t < 64) {
        v0 = b0[t];
        for (int k = 0; k < 64; ++k) v0 = fmaf(hb[k], W0[k * 64 + t], v0);
        v0 = fmaxf(v0, 0.f);
    }
    __syncthreads(); if (t < 64) hb[t] = v0; __syncthreads();
    if (t < 64) {
        v0 = b1[t];
        for (int k = 0; k < 64; ++k) v0 = fmaf(hb[k], W1[k * 64 + t], v0);
        v0 = fmaxf(v0, 0.f);
    }
    __syncthreads(); if (t < 64) hb[t] = v0; __syncthreads();
    if (t < 64) {
        v0 = b2[t];
        for (int k = 0; k < 64; ++k) v0 = fmaf(hb[k], W2[k * 64 + t], v0);
        v0 = fmaxf(v0, 0.f);
    }
    __syncthreads(); if (t < 64) hb[t] = v0; __syncthreads();
    if (t < 64) {
        float r = hb[t] * W3[t];
        #pragma unroll
        for (int off = 32; off; off >>= 1) r += __shfl_xor(r, off);
        if (t == 0) out[b] = r + b3[0];
    }
}

extern "C" void kernel_launch(void* const* d_in, const int* in_sizes, int n_in,
                              void* d_out, int out_size, void* d_ws, size_t ws_size,
                              hipStream_t stream)
{
    const float* node_feats = (const float*)d_in[0];
    const float* glob       = (const float*)d_in[1];
    const int*   edge_index = (const int*)d_in[2];
    const int*   batch      = (const int*)d_in[3];
    const float* W[3]  = {(const float*)d_in[4],  (const float*)d_in[8],  (const float*)d_in[12]};
    const float* As[3] = {(const float*)d_in[5],  (const float*)d_in[9],  (const float*)d_in[13]};
    const float* Ad[3] = {(const float*)d_in[6],  (const float*)d_in[10], (const float*)d_in[14]};
    const float* Bi[3] = {(const float*)d_in[7],  (const float*)d_in[11], (const float*)d_in[15]};
    const float* mW0 = (const float*)d_in[16]; const float* mb0 = (const float*)d_in[17];
    const float* mW1 = (const float*)d_in[18]; const float* mb1 = (const float*)d_in[19];
    const float* mW2 = (const float*)d_in[20]; const float* mb2 = (const float*)d_in[21];
    const float* mW3 = (const float*)d_in[22]; const float* mb3 = (const float*)d_in[23];
    float* out = (float*)d_out;

    int N = in_sizes[0] / 9;
    int E = in_sizes[2] / 2;
    int B = in_sizes[1] / 4;
    const int* esrc = edge_index;
    const int* edst = edge_index + E;
    int nb = (N + DB - 1) / DB;

    // workspace layout
    char* ws = (char*)d_ws;
    size_t off = 0;
    auto alloc = [&](size_t bytes) -> void* {
        void* p = ws + off;
        off = (off + bytes + 255) & ~(size_t)255;
        return p;
    };
    __half*   hbuf     = (__half*)alloc((size_t)N * 64 * 2);
    float*    xbuf     = (float*)alloc((size_t)N * 64 * 4);
    float*    asrc     = (float*)alloc((size_t)N * GAT_H * 4);
    float*    adst     = (float*)alloc((size_t)N * GAT_H * 4);
    int*      indptr   = (int*)alloc((size_t)(N + 1) * 4);
    int*      csr_src  = (int*)alloc((size_t)(E + 16) * 4);
    unsigned* binned   = (unsigned*)alloc((size_t)E * 4);
    unsigned* slices   = (unsigned*)alloc((size_t)SLICES * NBMAX * 4);
    unsigned* bin_base = (unsigned*)alloc((NBMAX + 1) * 4);
    unsigned* bin_fill = (unsigned*)alloc(NBMAX * 4);
    (void)ws_size;

    // CSR build (binned counting sort; once — shared by all 3 layers)
    hist_bins<<<SLICES, 256, 0, stream>>>(edst, slices, E);
    scan_bins<<<1, 256, 0, stream>>>(slices, bin_base, bin_fill, indptr, SLICES, N, E);
    bin_scatter<<<(E + CHUNK - 1) / CHUNK, 256, 0, stream>>>(esrc, edst, bin_base, bin_fill,
                                                             binned, E);
    bin_finalize<<<nb, 256, 0, stream>>>(binned, bin_base, csr_src, indptr, N, E);

    const int gemmBlocks = 1024;
    const int aggBlocks = 12500;    // 50000 waves -> 1 node per wave
    // layer 0 (K=13, concat fused)
    gemm_attn<13, true><<<gemmBlocks, 256, 0, stream>>>(nullptr, node_feats, glob, batch,
                                                        W[0], As[0], Ad[0], hbuf, asrc, adst,
                                                        N, gemmBlocks * 4);
    aggregate3<true><<<aggBlocks, 256, 0, stream>>>(hbuf, asrc, adst, indptr, csr_src, Bi[0],
                                                    xbuf, N, aggBlocks * 4);
    // layer 1 (K=64)
    gemm_attn<64, false><<<gemmBlocks, 256, 0, stream>>>(xbuf, nullptr, nullptr, nullptr,
                                                         W[1], As[1], Ad[1], hbuf, asrc, adst,
                                                         N, gemmBlocks * 4);
    aggregate3<true><<<aggBlocks, 256, 0, stream>>>(hbuf, asrc, adst, indptr, csr_src, Bi[1],
                                                    xbuf, N, aggBlocks * 4);
    // layer 2 (K=64, no act)
    gemm_attn<64, false><<<gemmBlocks, 256, 0, stream>>>(xbuf, nullptr, nullptr, nullptr,
                                                         W[2], As[2], Ad[2], hbuf, asrc, adst,
                                                         N, gemmBlocks * 4);
    aggregate3<false><<<aggBlocks, 256, 0, stream>>>(hbuf, asrc, adst, indptr, csr_src, Bi[2],
                                                     xbuf, N, aggBlocks * 4);

    // fused pooling + MLP head
    pool_mlp<<<B, 256, 0, stream>>>(xbuf, batch, N,
                                    mW0, mb0, mW1, mb1, mW2, mb2, mW3, mb3, out);
}